// Round 2
// baseline (194.294 us; speedup 1.0000x reference)
//
#include <hip/hip_runtime.h>

// SelfAttention: x[8,2048,512] f32, W[3,512,512] f32 -> out[8,2048,512] f32
// scale = 1/sqrt(64) = 0.125 (module hardcodes 64, not d)
//
// Pipeline (all bf16 MFMA, fp32 accum):
//  1. convert x -> bf16            2. transpose+convert W -> Wt bf16
//  3. QKV gemm (C = A.Bt form)     4. scores = Q.Kt * 0.125 -> bf16
//  5. row softmax in place         6. out = P.V (via Vt) -> f32, split-K x2
//
// R2: double-buffered prefetch mainloop (issue next-tile global_load_lds
// before MFMA, single barrier/iter); PV uses 8 waves = 2 K-groups + LDS
// reduction to fix its occupancy (512 blocks -> was 8 waves/CU, now 16).

typedef unsigned short u16;
typedef unsigned int u32;

using bf16x8 = __attribute__((ext_vector_type(8))) short;   // 8 bf16 (4 VGPRs)
using f32x4  = __attribute__((ext_vector_type(4))) float;
using u16x4  = __attribute__((ext_vector_type(4))) u16;

__device__ __forceinline__ u16 f2bf(float f) {
  u32 u = __float_as_uint(f);
  u32 r = (u + 0x7FFFu + ((u >> 16) & 1u)) >> 16;   // RNE
  return (u16)r;
}
__device__ __forceinline__ float bf2f(u16 h) {
  return __uint_as_float(((u32)h) << 16);
}

#define GLL16(src, dst)                                                        \
  __builtin_amdgcn_global_load_lds(                                            \
      (const __attribute__((address_space(1))) void*)(src),                    \
      (__attribute__((address_space(3))) void*)(dst), 16, 0, 0)

// ---------------------------------------------------------------------------
// GEMM mainloop: C[128x128] += A[128xK_g] . B[128xK_g]^T (row-major, K
// contiguous). KG=1: 4 waves (2x2), full K. KG=2: 8 waves, wave w>>2 = K-group
// g handles K-half g with its own LDS double-buffer; caller reduces.
// LDS layout per group: 2 buffers x (As[128][32] + Bs[128][32]) = 16 KB.
// ---------------------------------------------------------------------------
template <int KG>
__device__ __forceinline__ void gemm_bt_mainloop(
    const u16* __restrict__ Ab,   // A base incl. m0*K
    const u16* __restrict__ Bb,   // B base incl. n0*K
    int K, u16* lds, f32x4 (&acc)[4][4])
{
  const int tid = threadIdx.x;
  const int w = tid >> 6, l = tid & 63;
  const int g  = (KG == 1) ? 0 : (w >> 2);
  const int wl = (KG == 1) ? w : (w & 3);
  const int wr = wl >> 1, wc = wl & 1;
  const int srow = l >> 2;            // staging: 4 lanes per 64B row-chunk
  const int skof = (l & 3) * 8;       // staging k offset (elems)
  const int fr = l & 15;              // frag row/col
  const int k8 = (l >> 4) * 8;        // frag k base (elems)

  const int Kg = K / KG;
  u16* base = lds + g * 16384;        // per-group: 2 x 8192 u16 buffers
  const u16* aS = Ab + (size_t)(wl * 32 + srow) * K + g * Kg + skof;
  const u16* bS = Bb + (size_t)(wl * 32 + srow) * K + g * Kg + skof;
  const int rowK16 = 16 * K;

  auto STAGE = [&](int kt, int c) {
    u16* aD = base + c * 8192 + wl * 1024;   // wave-uniform; HW adds lane*16B
    u16* bD = aD + 4096;
    GLL16(aS + kt, aD);
    GLL16(aS + kt + rowK16, aD + 512);
    GLL16(bS + kt, bD);
    GLL16(bS + kt + rowK16, bD + 512);
  };

  STAGE(0, 0);
  __syncthreads();                    // compiler drains vmcnt before s_barrier
  int cur = 0;
  for (int kt = 0; kt < Kg; kt += 32) {
    if (kt + 32 < Kg) STAGE(kt + 32, cur ^ 1);   // prefetch overlaps MFMA

    const u16* As = base + cur * 8192;
    const u16* Bs = As + 4096;
    bf16x8 a[4], b[4];
#pragma unroll
    for (int mi = 0; mi < 4; ++mi)
      a[mi] = *(const bf16x8*)(As + (wr * 64 + mi * 16 + fr) * 32 + k8);
#pragma unroll
    for (int ni = 0; ni < 4; ++ni)
      b[ni] = *(const bf16x8*)(Bs + (wc * 64 + ni * 16 + fr) * 32 + k8);
#pragma unroll
    for (int mi = 0; mi < 4; ++mi)
#pragma unroll
      for (int ni = 0; ni < 4; ++ni)
        acc[mi][ni] = __builtin_amdgcn_mfma_f32_16x16x32_bf16(a[mi], b[ni], acc[mi][ni], 0, 0, 0);

    __syncthreads();                  // next buffer staged; cur consumed
    cur ^= 1;
  }
}

// ---------------------------------------------------------------------------
// Kernels
// ---------------------------------------------------------------------------

__global__ void convert_x_kernel(const float* __restrict__ x, u16* __restrict__ xb) {
  int i = blockIdx.x * 256 + threadIdx.x;       // 2,097,152 threads * 4 floats
  float4 f = ((const float4*)x)[i];
  u16x4 o = { f2bf(f.x), f2bf(f.y), f2bf(f.z), f2bf(f.w) };
  ((u16x4*)xb)[i] = o;
}

// W[m][d][e] f32 -> Wt[m][e][d] bf16 (LDS-tiled transpose)
__global__ void convw_kernel(const float* __restrict__ W, u16* __restrict__ wT) {
  __shared__ float tile[32][33];
  const int mtx = blockIdx.z;
  const int e0 = blockIdx.x * 32, d0 = blockIdx.y * 32;
  const int tx = threadIdx.x, ty = threadIdx.y;  // (32, 8)
  const float* Wm = W + (size_t)mtx * 262144;
#pragma unroll
  for (int i = 0; i < 32; i += 8)
    tile[ty + i][tx] = Wm[(size_t)(d0 + ty + i) * 512 + e0 + tx];
  __syncthreads();
  u16* T = wT + (size_t)mtx * 262144;
#pragma unroll
  for (int i = 0; i < 32; i += 8)
    T[(size_t)(e0 + ty + i) * 512 + d0 + tx] = f2bf(tile[tx][ty + i]);
}

// QKV: xb[16384,512] . Wt[1536,512]^T ; q,k stored [16384,512], v stored
// transposed per batch vt[b][512][2048].
__global__ __launch_bounds__(256) void gemm_qkv_kernel(
    const u16* __restrict__ xb, const u16* __restrict__ wT,
    u16* __restrict__ qb, u16* __restrict__ kb, u16* __restrict__ vt)
{
  __shared__ __align__(16) u16 lds[16384];
  const int n0 = blockIdx.x * 128, m0 = blockIdx.y * 128;
  f32x4 acc[4][4] = {};
  gemm_bt_mainloop<1>(xb + (size_t)m0 * 512, wT + (size_t)n0 * 512, 512, lds, acc);

  const int tid = threadIdx.x, w = tid >> 6, l = tid & 63;
  const int wr = w >> 1, wc = w & 1;
  const int which = n0 >> 9;                 // 0=q 1=k 2=v
  const int e0 = (n0 & 511) + wc * 64;
  const int r0 = m0 + wr * 64;
  if (which < 2) {
    u16* dst = which ? kb : qb;
#pragma unroll
    for (int mi = 0; mi < 4; ++mi)
#pragma unroll
      for (int ni = 0; ni < 4; ++ni) {
        const int rowb = r0 + mi * 16 + (l >> 4) * 4;
        const int col = e0 + ni * 16 + (l & 15);
#pragma unroll
        for (int r = 0; r < 4; ++r)
          dst[(size_t)(rowb + r) * 512 + col] = f2bf(acc[mi][ni][r]);
      }
  } else {
#pragma unroll
    for (int mi = 0; mi < 4; ++mi)
#pragma unroll
      for (int ni = 0; ni < 4; ++ni) {
        const int s = r0 + mi * 16 + (l >> 4) * 4;   // global row (b*2048+s)
        const int b = s >> 11, sl = s & 2047;
        const int e = e0 + ni * 16 + (l & 15);
        u16x4 pk;
#pragma unroll
        for (int r = 0; r < 4; ++r) pk[r] = f2bf(acc[mi][ni][r]);
        *(u16x4*)(vt + (size_t)b * 1048576 + (size_t)e * 2048 + sl) = pk;
      }
  }
}

// scores[z] = Q[z] . K[z]^T * 0.125 -> bf16
__global__ __launch_bounds__(256) void gemm_scores_kernel(
    const u16* __restrict__ qb, const u16* __restrict__ kb, u16* __restrict__ attn)
{
  __shared__ __align__(16) u16 lds[16384];
  const int z = blockIdx.z;
  const int n0 = blockIdx.x * 128, m0 = blockIdx.y * 128;
  f32x4 acc[4][4] = {};
  gemm_bt_mainloop<1>(qb + (size_t)z * 1048576 + (size_t)m0 * 512,
                      kb + (size_t)z * 1048576 + (size_t)n0 * 512, 512, lds, acc);
  const int tid = threadIdx.x, w = tid >> 6, l = tid & 63;
  const int wr = w >> 1, wc = w & 1;
  u16* C = attn + (size_t)z * 4194304;
#pragma unroll
  for (int mi = 0; mi < 4; ++mi)
#pragma unroll
    for (int ni = 0; ni < 4; ++ni) {
      const int rowb = m0 + wr * 64 + mi * 16 + (l >> 4) * 4;
      const int col = n0 + wc * 64 + ni * 16 + (l & 15);
#pragma unroll
      for (int r = 0; r < 4; ++r)
        C[(size_t)(rowb + r) * 2048 + col] = f2bf(acc[mi][ni][r] * 0.125f);
    }
}

// row softmax in place, bf16 storage, fp32 math. one block per row of 2048.
__global__ __launch_bounds__(256) void softmax_kernel(u16* __restrict__ attn) {
  __shared__ float redm[4], reds[4];
  const size_t row = blockIdx.x;
  u16* p = attn + row * 2048;
  const int t = threadIdx.x, w = t >> 6, l = t & 63;

  uint4 u = ((const uint4*)p)[t];
  u16* us = (u16*)&u;
  float v[8];
#pragma unroll
  for (int i = 0; i < 8; ++i) v[i] = bf2f(us[i]);

  float m = v[0];
#pragma unroll
  for (int i = 1; i < 8; ++i) m = fmaxf(m, v[i]);
  for (int off = 32; off >= 1; off >>= 1) m = fmaxf(m, __shfl_xor(m, off));
  if (l == 0) redm[w] = m;
  __syncthreads();
  m = fmaxf(fmaxf(redm[0], redm[1]), fmaxf(redm[2], redm[3]));

  float e[8], s = 0.f;
#pragma unroll
  for (int i = 0; i < 8; ++i) { e[i] = __expf(v[i] - m); s += e[i]; }
  for (int off = 32; off >= 1; off >>= 1) s += __shfl_xor(s, off);
  if (l == 0) reds[w] = s;
  __syncthreads();
  s = reds[0] + reds[1] + reds[2] + reds[3];
  const float inv = 1.f / s;

#pragma unroll
  for (int i = 0; i < 8; ++i) us[i] = f2bf(e[i] * inv);
  ((uint4*)p)[t] = u;
}

// out[z] = P[z][2048,2048] . V[z] (V held transposed: vt[z][512][2048]) -> f32
// 8 waves: K-groups g=0,1 each do K/2; LDS reduction (2 rounds of 32 KB
// reusing the staging buffer), group 0 stores.
__global__ __launch_bounds__(512, 4) void gemm_pv_kernel(
    const u16* __restrict__ attn, const u16* __restrict__ vt, float* __restrict__ out)
{
  __shared__ __align__(16) u16 lds[32768];   // 64 KB: 2 groups x 2 buffers
  const int z = blockIdx.z;
  const int n0 = blockIdx.x * 128, m0 = blockIdx.y * 128;
  f32x4 acc[4][4] = {};
  gemm_bt_mainloop<2>(attn + (size_t)z * 4194304 + (size_t)m0 * 2048,
                      vt + (size_t)z * 1048576 + (size_t)n0 * 2048, 2048, lds, acc);

  const int tid = threadIdx.x, w = tid >> 6, l = tid & 63;
  const int g = w >> 2, wl = w & 3;
  const int wr = wl >> 1, wc = wl & 1;
  float* red = (float*)lds;                  // [64][128] f32 = 32 KB per round
#pragma unroll
  for (int h = 0; h < 2; ++h) {
    __syncthreads();
    if (g == 1) {
#pragma unroll
      for (int mi2 = 0; mi2 < 2; ++mi2)
#pragma unroll
        for (int ni = 0; ni < 4; ++ni)
#pragma unroll
          for (int r = 0; r < 4; ++r)
            red[(wr * 32 + mi2 * 16 + (l >> 4) * 4 + r) * 128 + wc * 64 + ni * 16 + (l & 15)]
                = acc[h * 2 + mi2][ni][r];
    }
    __syncthreads();
    if (g == 0) {
#pragma unroll
      for (int mi2 = 0; mi2 < 2; ++mi2)
#pragma unroll
        for (int ni = 0; ni < 4; ++ni)
#pragma unroll
          for (int r = 0; r < 4; ++r)
            acc[h * 2 + mi2][ni][r]
                += red[(wr * 32 + mi2 * 16 + (l >> 4) * 4 + r) * 128 + wc * 64 + ni * 16 + (l & 15)];
    }
  }
  if (g == 0) {
    float* C = out + (size_t)z * 1048576;
#pragma unroll
    for (int mi = 0; mi < 4; ++mi)
#pragma unroll
      for (int ni = 0; ni < 4; ++ni) {
        const int rowb = m0 + wr * 64 + mi * 16 + (l >> 4) * 4;
        const int col = n0 + wc * 64 + ni * 16 + (l & 15);
#pragma unroll
        for (int r = 0; r < 4; ++r)
          C[(size_t)(rowb + r) * 512 + col] = acc[mi][ni][r];
      }
  }
}

// ---------------------------------------------------------------------------
extern "C" void kernel_launch(void* const* d_in, const int* in_sizes, int n_in,
                              void* d_out, int out_size, void* d_ws, size_t ws_size,
                              hipStream_t stream) {
  const float* x = (const float*)d_in[0];   // [8,2048,512]
  const float* W = (const float*)d_in[1];   // [3,512,512]
  float* out = (float*)d_out;               // [8,2048,512]

  // workspace layout (u16 elems): qb | kb | vt | attn(67MB; xb+wT aliased in)
  if (ws_size < 117440512) return;          // 112 MiB needed
  u16* wsu  = (u16*)d_ws;
  u16* qb   = wsu;
  u16* kb   = qb + 8388608;
  u16* vt   = kb + 8388608;
  u16* attn = vt + 8388608;                 // 33,554,432 elems
  u16* xb   = attn;                         // alias: dead before scores written
  u16* wT   = attn + 8388608;               // alias: dead before scores written

  convert_x_kernel<<<8192, 256, 0, stream>>>(x, xb);
  convw_kernel<<<dim3(16, 16, 3), dim3(32, 8), 0, stream>>>(W, wT);
  gemm_qkv_kernel<<<dim3(12, 128), 256, 0, stream>>>(xb, wT, qb, kb, vt);
  gemm_scores_kernel<<<dim3(16, 16, 8), 256, 0, stream>>>(qb, kb, attn);
  softmax_kernel<<<16384, 256, 0, stream>>>(attn);
  gemm_pv_kernel<<<dim3(4, 16, 8), 512, 0, stream>>>(attn, vt, out);
}

// Round 3
// 187.148 us; speedup vs baseline: 1.0382x; 1.0382x over previous
//
#include <hip/hip_runtime.h>

// SelfAttention: x[8,2048,512] f32, W[3,512,512] f32 -> out[8,2048,512] f32
// scale = 1/sqrt(64) = 0.125 (module hardcodes 64, not d)
//
// Pipeline (all bf16 MFMA, fp32 accum):
//  1. convert x -> bf16            2. transpose+convert W -> Wt bf16
//  3. QKV gemm (C = A.Bt form)     4. scores = Q.Kt * 0.125 -> bf16
//  5. row softmax in place         6. out = P.V (via Vt) -> f32, split-K x2
//
// R3: reverted R2's explicit double-buffer (regressed qkv 40->60us: +LDS
// +VGPR cut occupancy; barrier still drains vmcnt - m99/m100 lesson).
// Single-buffer 2-barrier m97 mainloop, templated KG; PV keeps 8-wave
// split-K (fixed its R1 latency-bound 21% MfmaUtil) now at 32KB LDS.

typedef unsigned short u16;
typedef unsigned int u32;

using bf16x8 = __attribute__((ext_vector_type(8))) short;   // 8 bf16 (4 VGPRs)
using f32x4  = __attribute__((ext_vector_type(4))) float;
using u16x4  = __attribute__((ext_vector_type(4))) u16;

__device__ __forceinline__ u16 f2bf(float f) {
  u32 u = __float_as_uint(f);
  u32 r = (u + 0x7FFFu + ((u >> 16) & 1u)) >> 16;   // RNE
  return (u16)r;
}
__device__ __forceinline__ float bf2f(u16 h) {
  return __uint_as_float(((u32)h) << 16);
}

#define GLL16(src, dst)                                                        \
  __builtin_amdgcn_global_load_lds(                                            \
      (const __attribute__((address_space(1))) void*)(src),                    \
      (__attribute__((address_space(3))) void*)(dst), 16, 0, 0)

// ---------------------------------------------------------------------------
// GEMM mainloop: C[128x128] += A[128xK_g] . B[128xK_g]^T (row-major, K
// contiguous). KG=1: 4 waves (2x2), full K. KG=2: 8 waves, K-group g = w>>2
// handles K-half g into private acc with its own 16KB LDS; caller reduces.
// ---------------------------------------------------------------------------
template <int KG>
__device__ __forceinline__ void gemm_bt_mainloop(
    const u16* __restrict__ Ab,   // A base incl. m0*K
    const u16* __restrict__ Bb,   // B base incl. n0*K
    int K, u16* lds, f32x4 (&acc)[4][4])
{
  const int tid = threadIdx.x;
  const int w = tid >> 6, l = tid & 63;
  const int g  = (KG == 1) ? 0 : (w >> 2);
  const int wl = (KG == 1) ? w : (w & 3);
  const int wr = wl >> 1, wc = wl & 1;
  const int srow = l >> 2;            // staging: 4 lanes per 64B row-chunk
  const int skof = (l & 3) * 8;       // staging k offset (elems)
  const int fr = l & 15;              // frag row/col
  const int k8 = (l >> 4) * 8;        // frag k base (elems)

  const int Kg = K / KG;
  u16* base = lds + g * 8192;         // per-group As[128][32] + Bs[128][32]
  const u16* aS = Ab + (size_t)(wl * 32 + srow) * K + g * Kg + skof;
  const u16* bS = Bb + (size_t)(wl * 32 + srow) * K + g * Kg + skof;
  u16* aD = base + wl * 1024;         // wave-uniform; HW adds lane*16B
  u16* bD = aD + 4096;
  const int rowK16 = 16 * K;

  for (int kt = 0; kt < Kg; kt += 32) {
    __syncthreads();  // previous tile fully consumed
    GLL16(aS + kt, aD);
    GLL16(aS + kt + rowK16, aD + 512);
    GLL16(bS + kt, bD);
    GLL16(bS + kt + rowK16, bD + 512);
    __syncthreads();  // compiler drains vmcnt before s_barrier -> LDS valid

    const u16* As = base;
    const u16* Bs = base + 4096;
    bf16x8 a[4], b[4];
#pragma unroll
    for (int mi = 0; mi < 4; ++mi)
      a[mi] = *(const bf16x8*)(As + (wr * 64 + mi * 16 + fr) * 32 + k8);
#pragma unroll
    for (int ni = 0; ni < 4; ++ni)
      b[ni] = *(const bf16x8*)(Bs + (wc * 64 + ni * 16 + fr) * 32 + k8);
#pragma unroll
    for (int mi = 0; mi < 4; ++mi)
#pragma unroll
      for (int ni = 0; ni < 4; ++ni)
        acc[mi][ni] = __builtin_amdgcn_mfma_f32_16x16x32_bf16(a[mi], b[ni], acc[mi][ni], 0, 0, 0);
  }
}

// ---------------------------------------------------------------------------
// Kernels
// ---------------------------------------------------------------------------

__global__ void convert_x_kernel(const float* __restrict__ x, u16* __restrict__ xb) {
  int i = blockIdx.x * 256 + threadIdx.x;       // 2,097,152 threads * 4 floats
  float4 f = ((const float4*)x)[i];
  u16x4 o = { f2bf(f.x), f2bf(f.y), f2bf(f.z), f2bf(f.w) };
  ((u16x4*)xb)[i] = o;
}

// W[m][d][e] f32 -> Wt[m][e][d] bf16 (LDS-tiled transpose)
__global__ void convw_kernel(const float* __restrict__ W, u16* __restrict__ wT) {
  __shared__ float tile[32][33];
  const int mtx = blockIdx.z;
  const int e0 = blockIdx.x * 32, d0 = blockIdx.y * 32;
  const int tx = threadIdx.x, ty = threadIdx.y;  // (32, 8)
  const float* Wm = W + (size_t)mtx * 262144;
#pragma unroll
  for (int i = 0; i < 32; i += 8)
    tile[ty + i][tx] = Wm[(size_t)(d0 + ty + i) * 512 + e0 + tx];
  __syncthreads();
  u16* T = wT + (size_t)mtx * 262144;
#pragma unroll
  for (int i = 0; i < 32; i += 8)
    T[(size_t)(e0 + ty + i) * 512 + d0 + tx] = f2bf(tile[tx][ty + i]);
}

// QKV: xb[16384,512] . Wt[1536,512]^T ; q,k stored [16384,512], v stored
// transposed per batch vt[b][512][2048].
__global__ __launch_bounds__(256) void gemm_qkv_kernel(
    const u16* __restrict__ xb, const u16* __restrict__ wT,
    u16* __restrict__ qb, u16* __restrict__ kb, u16* __restrict__ vt)
{
  __shared__ __align__(16) u16 lds[8192];
  const int n0 = blockIdx.x * 128, m0 = blockIdx.y * 128;
  f32x4 acc[4][4] = {};
  gemm_bt_mainloop<1>(xb + (size_t)m0 * 512, wT + (size_t)n0 * 512, 512, lds, acc);

  const int tid = threadIdx.x, w = tid >> 6, l = tid & 63;
  const int wr = w >> 1, wc = w & 1;
  const int which = n0 >> 9;                 // 0=q 1=k 2=v
  const int e0 = (n0 & 511) + wc * 64;
  const int r0 = m0 + wr * 64;
  if (which < 2) {
    u16* dst = which ? kb : qb;
#pragma unroll
    for (int mi = 0; mi < 4; ++mi)
#pragma unroll
      for (int ni = 0; ni < 4; ++ni) {
        const int rowb = r0 + mi * 16 + (l >> 4) * 4;
        const int col = e0 + ni * 16 + (l & 15);
#pragma unroll
        for (int r = 0; r < 4; ++r)
          dst[(size_t)(rowb + r) * 512 + col] = f2bf(acc[mi][ni][r]);
      }
  } else {
#pragma unroll
    for (int mi = 0; mi < 4; ++mi)
#pragma unroll
      for (int ni = 0; ni < 4; ++ni) {
        const int s = r0 + mi * 16 + (l >> 4) * 4;   // global row (b*2048+s)
        const int b = s >> 11, sl = s & 2047;
        const int e = e0 + ni * 16 + (l & 15);
        u16x4 pk;
#pragma unroll
        for (int r = 0; r < 4; ++r) pk[r] = f2bf(acc[mi][ni][r]);
        *(u16x4*)(vt + (size_t)b * 1048576 + (size_t)e * 2048 + sl) = pk;
      }
  }
}

// scores[z] = Q[z] . K[z]^T * 0.125 -> bf16
__global__ __launch_bounds__(256) void gemm_scores_kernel(
    const u16* __restrict__ qb, const u16* __restrict__ kb, u16* __restrict__ attn)
{
  __shared__ __align__(16) u16 lds[8192];
  const int z = blockIdx.z;
  const int n0 = blockIdx.x * 128, m0 = blockIdx.y * 128;
  f32x4 acc[4][4] = {};
  gemm_bt_mainloop<1>(qb + (size_t)z * 1048576 + (size_t)m0 * 512,
                      kb + (size_t)z * 1048576 + (size_t)n0 * 512, 512, lds, acc);
  const int tid = threadIdx.x, w = tid >> 6, l = tid & 63;
  const int wr = w >> 1, wc = w & 1;
  u16* C = attn + (size_t)z * 4194304;
#pragma unroll
  for (int mi = 0; mi < 4; ++mi)
#pragma unroll
    for (int ni = 0; ni < 4; ++ni) {
      const int rowb = m0 + wr * 64 + mi * 16 + (l >> 4) * 4;
      const int col = n0 + wc * 64 + ni * 16 + (l & 15);
#pragma unroll
      for (int r = 0; r < 4; ++r)
        C[(size_t)(rowb + r) * 2048 + col] = f2bf(acc[mi][ni][r] * 0.125f);
    }
}

// row softmax in place, bf16 storage, fp32 math. one block per row of 2048.
__global__ __launch_bounds__(256) void softmax_kernel(u16* __restrict__ attn) {
  __shared__ float redm[4], reds[4];
  const size_t row = blockIdx.x;
  u16* p = attn + row * 2048;
  const int t = threadIdx.x, w = t >> 6, l = t & 63;

  uint4 u = ((const uint4*)p)[t];
  u16* us = (u16*)&u;
  float v[8];
#pragma unroll
  for (int i = 0; i < 8; ++i) v[i] = bf2f(us[i]);

  float m = v[0];
#pragma unroll
  for (int i = 1; i < 8; ++i) m = fmaxf(m, v[i]);
  for (int off = 32; off >= 1; off >>= 1) m = fmaxf(m, __shfl_xor(m, off));
  if (l == 0) redm[w] = m;
  __syncthreads();
  m = fmaxf(fmaxf(redm[0], redm[1]), fmaxf(redm[2], redm[3]));

  float e[8], s = 0.f;
#pragma unroll
  for (int i = 0; i < 8; ++i) { e[i] = __expf(v[i] - m); s += e[i]; }
  for (int off = 32; off >= 1; off >>= 1) s += __shfl_xor(s, off);
  if (l == 0) reds[w] = s;
  __syncthreads();
  s = reds[0] + reds[1] + reds[2] + reds[3];
  const float inv = 1.f / s;

#pragma unroll
  for (int i = 0; i < 8; ++i) us[i] = f2bf(e[i] * inv);
  ((uint4*)p)[t] = u;
}

// out[z] = P[z][2048,2048] . V[z] (V held transposed: vt[z][512][2048]) -> f32
// 8 waves: K-groups g=0,1 each do K/2; LDS reduction (2 rounds of 32 KB
// reusing the staging buffer), group 0 stores.
__global__ __launch_bounds__(512, 4) void gemm_pv_kernel(
    const u16* __restrict__ attn, const u16* __restrict__ vt, float* __restrict__ out)
{
  __shared__ __align__(16) u16 lds[16384];   // 32 KB: 2 groups x 16 KB staging
  const int z = blockIdx.z;
  const int n0 = blockIdx.x * 128, m0 = blockIdx.y * 128;
  f32x4 acc[4][4] = {};
  gemm_bt_mainloop<2>(attn + (size_t)z * 4194304 + (size_t)m0 * 2048,
                      vt + (size_t)z * 1048576 + (size_t)n0 * 2048, 2048, lds, acc);

  const int tid = threadIdx.x, w = tid >> 6, l = tid & 63;
  const int g = w >> 2, wl = w & 3;
  const int wr = wl >> 1, wc = wl & 1;
  float* red = (float*)lds;                  // [64][128] f32 = 32 KB per round
#pragma unroll
  for (int h = 0; h < 2; ++h) {
    __syncthreads();
    if (g == 1) {
#pragma unroll
      for (int mi2 = 0; mi2 < 2; ++mi2)
#pragma unroll
        for (int ni = 0; ni < 4; ++ni)
#pragma unroll
          for (int r = 0; r < 4; ++r)
            red[(wr * 32 + mi2 * 16 + (l >> 4) * 4 + r) * 128 + wc * 64 + ni * 16 + (l & 15)]
                = acc[h * 2 + mi2][ni][r];
    }
    __syncthreads();
    if (g == 0) {
#pragma unroll
      for (int mi2 = 0; mi2 < 2; ++mi2)
#pragma unroll
        for (int ni = 0; ni < 4; ++ni)
#pragma unroll
          for (int r = 0; r < 4; ++r)
            acc[h * 2 + mi2][ni][r]
                += red[(wr * 32 + mi2 * 16 + (l >> 4) * 4 + r) * 128 + wc * 64 + ni * 16 + (l & 15)];
    }
  }
  if (g == 0) {
    float* C = out + (size_t)z * 1048576;
#pragma unroll
    for (int mi = 0; mi < 4; ++mi)
#pragma unroll
      for (int ni = 0; ni < 4; ++ni) {
        const int rowb = m0 + wr * 64 + mi * 16 + (l >> 4) * 4;
        const int col = n0 + wc * 64 + ni * 16 + (l & 15);
#pragma unroll
        for (int r = 0; r < 4; ++r)
          C[(size_t)(rowb + r) * 512 + col] = acc[mi][ni][r];
      }
  }
}

// ---------------------------------------------------------------------------
extern "C" void kernel_launch(void* const* d_in, const int* in_sizes, int n_in,
                              void* d_out, int out_size, void* d_ws, size_t ws_size,
                              hipStream_t stream) {
  const float* x = (const float*)d_in[0];   // [8,2048,512]
  const float* W = (const float*)d_in[1];   // [3,512,512]
  float* out = (float*)d_out;               // [8,2048,512]

  // workspace layout (u16 elems): qb | kb | vt | attn(67MB; xb+wT aliased in)
  if (ws_size < 117440512) return;          // 112 MiB needed
  u16* wsu  = (u16*)d_ws;
  u16* qb   = wsu;
  u16* kb   = qb + 8388608;
  u16* vt   = kb + 8388608;
  u16* attn = vt + 8388608;                 // 33,554,432 elems
  u16* xb   = attn;                         // alias: dead before scores written
  u16* wT   = attn + 8388608;               // alias: dead before scores written

  convert_x_kernel<<<8192, 256, 0, stream>>>(x, xb);
  convw_kernel<<<dim3(16, 16, 3), dim3(32, 8), 0, stream>>>(W, wT);
  gemm_qkv_kernel<<<dim3(12, 128), 256, 0, stream>>>(xb, wT, qb, kb, vt);
  gemm_scores_kernel<<<dim3(16, 16, 8), 256, 0, stream>>>(qb, kb, attn);
  softmax_kernel<<<16384, 256, 0, stream>>>(attn);
  gemm_pv_kernel<<<dim3(4, 16, 8), 512, 0, stream>>>(attn, vt, out);
}

// Round 4
// 175.216 us; speedup vs baseline: 1.1089x; 1.0681x over previous
//
#include <hip/hip_runtime.h>

// SelfAttention: x[8,2048,512] f32, W[3,512,512] f32 -> out[8,2048,512] f32
// scale = 1/sqrt(64) = 0.125
//
// R4: qkv + scores ported to 256x256-tile 8-phase schedule (T3+T4+T2+T5):
//   BK=64 processed as 2 K-slabs [256][32]; 3 LDS slots/matrix (96KB);
//   stage runs 2 slabs ahead -> constant counted gate vmcnt(4) (never 0);
//   XOR swizzle chunk^=(row>>1)&3 => 2-way (free) frag reads, source
//   pre-swizzled so global_load_lds dest stays linear; setprio around MFMA.
// PV stays on R3 split-K structure this round.

typedef unsigned short u16;
typedef unsigned int u32;

using bf16x8 = __attribute__((ext_vector_type(8))) short;   // 8 bf16 (4 VGPRs)
using f32x4  = __attribute__((ext_vector_type(4))) float;
using u16x4  = __attribute__((ext_vector_type(4))) u16;

__device__ __forceinline__ u16 f2bf(float f) {
  u32 u = __float_as_uint(f);
  u32 r = (u + 0x7FFFu + ((u >> 16) & 1u)) >> 16;   // RNE
  return (u16)r;
}
__device__ __forceinline__ float bf2f(u16 h) {
  return __uint_as_float(((u32)h) << 16);
}

#define GLL16(src, dst)                                                        \
  __builtin_amdgcn_global_load_lds(                                            \
      (const __attribute__((address_space(1))) void*)(src),                    \
      (__attribute__((address_space(3))) void*)(dst), 16, 0, 0)

// ---------------------------------------------------------------------------
// 8-phase 256x256 mainloop: C[256x256] += A[256xK] . B[256xK]^T, row-major.
// 512 threads = 8 waves (2M x 4N); per-wave 128x64 output = acc[8][4].
// K-slab j = [256 rows][k j*32..j*32+32), 16KB. Slots: A 3x16KB, B 3x16KB.
// Slab j read at iter j (2 phases: mi 0-3, mi 4-7); slab j staged at iter
// j-2 (B at even sub-phase, A at odd). Gate: vmcnt(4) covers A_j,B_j since
// exactly B_{j+1},A_{j+1} (4 loads) issue after A_j.  LDS swizzle: 16B-chunk
// index ^= (row>>1)&3 (2-way conflict = free); source pre-swizzled.
// ---------------------------------------------------------------------------
template <int K>
__device__ __forceinline__ void gemm8p_mainloop(
    const u16* __restrict__ A0,   // A base incl. m0*K
    const u16* __restrict__ B0,   // B base incl. n0*K
    u16* lds, f32x4 (&acc)[8][4])
{
  const int tid = threadIdx.x;
  const int w = tid >> 6, l = tid & 63;
  const int wm = w >> 2, wn = w & 3;
  const int fr = l & 15;
  const int laneChunk = ((l >> 4) ^ ((fr >> 1) & 3)) << 3;   // swizzled 16B chunk
  const int laneA = (wm * 128 + fr) * 32 + laneChunk;
  const int laneB = (wn * 64 + fr) * 32 + laneChunk;
  u16* const ldsA = lds;                 // 3 slots x 8192 u16
  u16* const ldsB = lds + 24576;

  // staging: thread covers rows r0, r0+128; 16B chunk (tid&3), pre-swizzled
  const int chunkS = ((tid & 3) ^ ((tid >> 3) & 3)) << 3;
  const int r0 = tid >> 2;
  const u16* const sA0 = A0 + (size_t)r0 * K + chunkS;
  const u16* const sA1 = A0 + (size_t)(r0 + 128) * K + chunkS;
  const u16* const sB0 = B0 + (size_t)r0 * K + chunkS;
  const u16* const sB1 = B0 + (size_t)(r0 + 128) * K + chunkS;
  const int dOf = w * 512;               // wave-uniform; HW adds lane*16B

#define STAGE_A(j, slot) do {                                                  \
    u16* d_ = ldsA + (slot) * 8192 + dOf;                                      \
    GLL16(sA0 + (j) * 32, d_);                                                 \
    GLL16(sA1 + (j) * 32, d_ + 4096);                                          \
  } while (0)
#define STAGE_B(j, slot) do {                                                  \
    u16* d_ = ldsB + (slot) * 8192 + dOf;                                      \
    GLL16(sB0 + (j) * 32, d_);                                                 \
    GLL16(sB1 + (j) * 32, d_ + 4096);                                          \
  } while (0)

  // prologue: slabs 0,1 for both matrices (B before A; A_j last => vmcnt math)
  STAGE_B(0, 0); STAGE_A(0, 0);
  STAGE_B(1, 1); STAGE_A(1, 1);

  constexpr int NS = K / 32;
  int slot = 0;
  for (int j = 0; j < NS; ++j) {
    const int jn = (j + 2 < NS) ? (j + 2) : (NS - 1);   // clamped (dup loads
    int slotn = slot + 2; if (slotn >= 3) slotn -= 3;   //  land in dead slot)

    // gate: A_j,B_j resident (4 newer loads allowed in flight); all waves
    asm volatile("s_waitcnt vmcnt(4)\n\ts_barrier" ::: "memory");

    const u16* const Ab = ldsA + slot * 8192;
    const u16* const Bb = ldsB + slot * 8192;
    bf16x8 a[4], b[4], a2[4];
#pragma unroll
    for (int i = 0; i < 4; ++i) a[i] = *(const bf16x8*)(Ab + laneA + i * 512);
#pragma unroll
    for (int i = 0; i < 4; ++i) b[i] = *(const bf16x8*)(Bb + laneB + i * 512);
    STAGE_B(jn, slotn);
    __builtin_amdgcn_s_setprio(1);
#pragma unroll
    for (int mi = 0; mi < 4; ++mi)
#pragma unroll
      for (int nj = 0; nj < 4; ++nj)
        acc[mi][nj] = __builtin_amdgcn_mfma_f32_16x16x32_bf16(a[mi], b[nj], acc[mi][nj], 0, 0, 0);
    __builtin_amdgcn_s_setprio(0);

#pragma unroll
    for (int i = 0; i < 4; ++i) a2[i] = *(const bf16x8*)(Ab + laneA + (4 + i) * 512);
    STAGE_A(jn, slotn);
    __builtin_amdgcn_s_setprio(1);
#pragma unroll
    for (int mi = 0; mi < 4; ++mi)
#pragma unroll
      for (int nj = 0; nj < 4; ++nj)
        acc[4 + mi][nj] = __builtin_amdgcn_mfma_f32_16x16x32_bf16(a2[mi], b[nj], acc[4 + mi][nj], 0, 0, 0);
    __builtin_amdgcn_s_setprio(0);
    asm volatile("s_barrier" ::: "memory");   // lockstep; recycle safety

    slot = (slot == 2) ? 0 : slot + 1;
  }
#undef STAGE_A
#undef STAGE_B
}

// ---------------------------------------------------------------------------
// old 128x128 mainloop (kept for PV split-K)
// ---------------------------------------------------------------------------
template <int KG>
__device__ __forceinline__ void gemm_bt_mainloop(
    const u16* __restrict__ Ab, const u16* __restrict__ Bb,
    int K, u16* lds, f32x4 (&acc)[4][4])
{
  const int tid = threadIdx.x;
  const int w = tid >> 6, l = tid & 63;
  const int g  = (KG == 1) ? 0 : (w >> 2);
  const int wl = (KG == 1) ? w : (w & 3);
  const int wr = wl >> 1, wc = wl & 1;
  const int srow = l >> 2;
  const int skof = (l & 3) * 8;
  const int fr = l & 15;
  const int k8 = (l >> 4) * 8;

  const int Kg = K / KG;
  u16* base = lds + g * 8192;
  const u16* aS = Ab + (size_t)(wl * 32 + srow) * K + g * Kg + skof;
  const u16* bS = Bb + (size_t)(wl * 32 + srow) * K + g * Kg + skof;
  u16* aD = base + wl * 1024;
  u16* bD = aD + 4096;
  const int rowK16 = 16 * K;

  for (int kt = 0; kt < Kg; kt += 32) {
    __syncthreads();
    GLL16(aS + kt, aD);
    GLL16(aS + kt + rowK16, aD + 512);
    GLL16(bS + kt, bD);
    GLL16(bS + kt + rowK16, bD + 512);
    __syncthreads();

    const u16* As = base;
    const u16* Bs = base + 4096;
    bf16x8 a[4], b[4];
#pragma unroll
    for (int mi = 0; mi < 4; ++mi)
      a[mi] = *(const bf16x8*)(As + (wr * 64 + mi * 16 + fr) * 32 + k8);
#pragma unroll
    for (int ni = 0; ni < 4; ++ni)
      b[ni] = *(const bf16x8*)(Bs + (wc * 64 + ni * 16 + fr) * 32 + k8);
#pragma unroll
    for (int mi = 0; mi < 4; ++mi)
#pragma unroll
      for (int ni = 0; ni < 4; ++ni)
        acc[mi][ni] = __builtin_amdgcn_mfma_f32_16x16x32_bf16(a[mi], b[ni], acc[mi][ni], 0, 0, 0);
  }
}

// ---------------------------------------------------------------------------
// Kernels
// ---------------------------------------------------------------------------

__global__ void convert_x_kernel(const float* __restrict__ x, u16* __restrict__ xb) {
  int i = blockIdx.x * 256 + threadIdx.x;
  float4 f = ((const float4*)x)[i];
  u16x4 o = { f2bf(f.x), f2bf(f.y), f2bf(f.z), f2bf(f.w) };
  ((u16x4*)xb)[i] = o;
}

__global__ void convw_kernel(const float* __restrict__ W, u16* __restrict__ wT) {
  __shared__ float tile[32][33];
  const int mtx = blockIdx.z;
  const int e0 = blockIdx.x * 32, d0 = blockIdx.y * 32;
  const int tx = threadIdx.x, ty = threadIdx.y;
  const float* Wm = W + (size_t)mtx * 262144;
#pragma unroll
  for (int i = 0; i < 32; i += 8)
    tile[ty + i][tx] = Wm[(size_t)(d0 + ty + i) * 512 + e0 + tx];
  __syncthreads();
  u16* T = wT + (size_t)mtx * 262144;
#pragma unroll
  for (int i = 0; i < 32; i += 8)
    T[(size_t)(e0 + ty + i) * 512 + d0 + tx] = f2bf(tile[tx][ty + i]);
}

// QKV via 8-phase 256^2: xb[16384,512] . wT[1536,512]^T
__global__ __launch_bounds__(512, 2) void gemm_qkv8p_kernel(
    const u16* __restrict__ xb, const u16* __restrict__ wT,
    u16* __restrict__ qb, u16* __restrict__ kb, u16* __restrict__ vt)
{
  __shared__ __align__(16) u16 lds[49152];   // 96 KB
  const int n0 = blockIdx.x * 256, m0 = blockIdx.y * 256;
  f32x4 acc[8][4] = {};
  gemm8p_mainloop<512>(xb + (size_t)m0 * 512, wT + (size_t)n0 * 512, lds, acc);

  const int tid = threadIdx.x, w = tid >> 6, l = tid & 63;
  const int wm = w >> 2, wn = w & 3;
  const int which = n0 >> 9;                  // bx: 0,1->q 2,3->k 4,5->v
  const int rb = m0 + wm * 128 + (l >> 4) * 4;
  const int e0 = (n0 & 511) + wn * 64 + (l & 15);
  if (which < 2) {
    u16* dst = which ? kb : qb;
#pragma unroll
    for (int mi = 0; mi < 8; ++mi)
#pragma unroll
      for (int nj = 0; nj < 4; ++nj) {
        const int row = rb + mi * 16;
        const int col = e0 + nj * 16;
#pragma unroll
        for (int r = 0; r < 4; ++r)
          dst[(size_t)(row + r) * 512 + col] = f2bf(acc[mi][nj][r]);
      }
  } else {
#pragma unroll
    for (int mi = 0; mi < 8; ++mi)
#pragma unroll
      for (int nj = 0; nj < 4; ++nj) {
        const int s = rb + mi * 16;             // global row (b*2048+s)
        const int b = s >> 11, sl = s & 2047;
        const int e = e0 + nj * 16;
        u16x4 pk;
#pragma unroll
        for (int r = 0; r < 4; ++r) pk[r] = f2bf(acc[mi][nj][r]);
        *(u16x4*)(vt + (size_t)b * 1048576 + (size_t)e * 2048 + sl) = pk;
      }
  }
}

// scores via 8-phase 256^2: Q[z].K[z]^T * 0.125 -> bf16
__global__ __launch_bounds__(512, 2) void gemm_scores8p_kernel(
    const u16* __restrict__ qb, const u16* __restrict__ kb, u16* __restrict__ attn)
{
  __shared__ __align__(16) u16 lds[49152];   // 96 KB
  const int z = blockIdx.z;
  const int n0 = blockIdx.x * 256, m0 = blockIdx.y * 256;
  f32x4 acc[8][4] = {};
  gemm8p_mainloop<512>(qb + (size_t)z * 1048576 + (size_t)m0 * 512,
                       kb + (size_t)z * 1048576 + (size_t)n0 * 512, lds, acc);

  const int tid = threadIdx.x, w = tid >> 6, l = tid & 63;
  const int wm = w >> 2, wn = w & 3;
  u16* C = attn + (size_t)z * 4194304;
  const int rb = m0 + wm * 128 + (l >> 4) * 4;
  const int cb = n0 + wn * 64 + (l & 15);
#pragma unroll
  for (int mi = 0; mi < 8; ++mi)
#pragma unroll
    for (int nj = 0; nj < 4; ++nj) {
      const int row = rb + mi * 16;
      const int col = cb + nj * 16;
#pragma unroll
      for (int r = 0; r < 4; ++r)
        C[(size_t)(row + r) * 2048 + col] = f2bf(acc[mi][nj][r] * 0.125f);
    }
}

// row softmax in place, bf16 storage, fp32 math. one block per row of 2048.
__global__ __launch_bounds__(256) void softmax_kernel(u16* __restrict__ attn) {
  __shared__ float redm[4], reds[4];
  const size_t row = blockIdx.x;
  u16* p = attn + row * 2048;
  const int t = threadIdx.x, w = t >> 6, l = t & 63;

  uint4 u = ((const uint4*)p)[t];
  u16* us = (u16*)&u;
  float v[8];
#pragma unroll
  for (int i = 0; i < 8; ++i) v[i] = bf2f(us[i]);

  float m = v[0];
#pragma unroll
  for (int i = 1; i < 8; ++i) m = fmaxf(m, v[i]);
  for (int off = 32; off >= 1; off >>= 1) m = fmaxf(m, __shfl_xor(m, off));
  if (l == 0) redm[w] = m;
  __syncthreads();
  m = fmaxf(fmaxf(redm[0], redm[1]), fmaxf(redm[2], redm[3]));

  float e[8], s = 0.f;
#pragma unroll
  for (int i = 0; i < 8; ++i) { e[i] = __expf(v[i] - m); s += e[i]; }
  for (int off = 32; off >= 1; off >>= 1) s += __shfl_xor(s, off);
  if (l == 0) reds[w] = s;
  __syncthreads();
  s = reds[0] + reds[1] + reds[2] + reds[3];
  const float inv = 1.f / s;

#pragma unroll
  for (int i = 0; i < 8; ++i) us[i] = f2bf(e[i] * inv);
  ((uint4*)p)[t] = u;
}

// out[z] = P[z][2048,2048] . V[z] (V transposed: vt[z][512][2048]) -> f32
__global__ __launch_bounds__(512, 4) void gemm_pv_kernel(
    const u16* __restrict__ attn, const u16* __restrict__ vt, float* __restrict__ out)
{
  __shared__ __align__(16) u16 lds[16384];
  const int z = blockIdx.z;
  const int n0 = blockIdx.x * 128, m0 = blockIdx.y * 128;
  f32x4 acc[4][4] = {};
  gemm_bt_mainloop<2>(attn + (size_t)z * 4194304 + (size_t)m0 * 2048,
                      vt + (size_t)z * 1048576 + (size_t)n0 * 2048, 2048, lds, acc);

  const int tid = threadIdx.x, w = tid >> 6, l = tid & 63;
  const int g = w >> 2, wl = w & 3;
  const int wr = wl >> 1, wc = wl & 1;
  float* red = (float*)lds;
#pragma unroll
  for (int h = 0; h < 2; ++h) {
    __syncthreads();
    if (g == 1) {
#pragma unroll
      for (int mi2 = 0; mi2 < 2; ++mi2)
#pragma unroll
        for (int ni = 0; ni < 4; ++ni)
#pragma unroll
          for (int r = 0; r < 4; ++r)
            red[(wr * 32 + mi2 * 16 + (l >> 4) * 4 + r) * 128 + wc * 64 + ni * 16 + (l & 15)]
                = acc[h * 2 + mi2][ni][r];
    }
    __syncthreads();
    if (g == 0) {
#pragma unroll
      for (int mi2 = 0; mi2 < 2; ++mi2)
#pragma unroll
        for (int ni = 0; ni < 4; ++ni)
#pragma unroll
          for (int r = 0; r < 4; ++r)
            acc[h * 2 + mi2][ni][r]
                += red[(wr * 32 + mi2 * 16 + (l >> 4) * 4 + r) * 128 + wc * 64 + ni * 16 + (l & 15)];
    }
  }
  if (g == 0) {
    float* C = out + (size_t)z * 1048576;
#pragma unroll
    for (int mi = 0; mi < 4; ++mi)
#pragma unroll
      for (int ni = 0; ni < 4; ++ni) {
        const int rowb = m0 + wr * 64 + mi * 16 + (l >> 4) * 4;
        const int col = n0 + wc * 64 + ni * 16 + (l & 15);
#pragma unroll
        for (int r = 0; r < 4; ++r)
          C[(size_t)(rowb + r) * 512 + col] = acc[mi][ni][r];
      }
  }
}

// ---------------------------------------------------------------------------
extern "C" void kernel_launch(void* const* d_in, const int* in_sizes, int n_in,
                              void* d_out, int out_size, void* d_ws, size_t ws_size,
                              hipStream_t stream) {
  const float* x = (const float*)d_in[0];   // [8,2048,512]
  const float* W = (const float*)d_in[1];   // [3,512,512]
  float* out = (float*)d_out;               // [8,2048,512]

  if (ws_size < 117440512) return;          // 112 MiB needed
  u16* wsu  = (u16*)d_ws;
  u16* qb   = wsu;
  u16* kb   = qb + 8388608;
  u16* vt   = kb + 8388608;
  u16* attn = vt + 8388608;
  u16* xb   = attn;                         // alias: dead before scores written
  u16* wT   = attn + 8388608;               // alias: dead before scores written

  convert_x_kernel<<<8192, 256, 0, stream>>>(x, xb);
  convw_kernel<<<dim3(16, 16, 3), dim3(32, 8), 0, stream>>>(W, wT);
  gemm_qkv8p_kernel<<<dim3(6, 64), 512, 0, stream>>>(xb, wT, qb, kb, vt);
  gemm_scores8p_kernel<<<dim3(8, 8, 8), 512, 0, stream>>>(qb, kb, attn);
  softmax_kernel<<<16384, 256, 0, stream>>>(attn);
  gemm_pv_kernel<<<dim3(4, 16, 8), 512, 0, stream>>>(attn, vt, out);
}

// Round 5
// 156.022 us; speedup vs baseline: 1.2453x; 1.1230x over previous
//
#include <hip/hip_runtime.h>

// SelfAttention: x[8,2048,512] f32, W[3,512,512] f32 -> out[8,2048,512] f32
// scale = 1/sqrt(64) = 0.125
//
// R5: PV ported to the 8-phase counted-vmcnt schedule with PV geometry:
//   tile 256x128 (grid 256 = 1/CU; 256x256 would leave half the GPU idle),
//   8 waves 4Mx2N, per-slab stage = 3 GLL16/wave (A 2 + B 1), gate vmcnt(3),
//   XOR-swizzled LDS via pre-swizzled source, setprio, z-per-XCD swizzle
//   (vt_z 2MB stays L2-resident per XCD; n-blocks sharing P co-locate).
// qkv + scores keep the validated R4 256^2 8-phase mainloop.

typedef unsigned short u16;
typedef unsigned int u32;

using bf16x8 = __attribute__((ext_vector_type(8))) short;   // 8 bf16 (4 VGPRs)
using f32x4  = __attribute__((ext_vector_type(4))) float;
using u16x4  = __attribute__((ext_vector_type(4))) u16;

__device__ __forceinline__ u16 f2bf(float f) {
  u32 u = __float_as_uint(f);
  u32 r = (u + 0x7FFFu + ((u >> 16) & 1u)) >> 16;   // RNE
  return (u16)r;
}
__device__ __forceinline__ float bf2f(u16 h) {
  return __uint_as_float(((u32)h) << 16);
}

#define GLL16(src, dst)                                                        \
  __builtin_amdgcn_global_load_lds(                                            \
      (const __attribute__((address_space(1))) void*)(src),                    \
      (__attribute__((address_space(3))) void*)(dst), 16, 0, 0)

// ---------------------------------------------------------------------------
// 8-phase 256x256 mainloop (qkv/scores): C[256x256] += A[256xK].B[256xK]^T.
// 512 threads = 8 waves (2M x 4N); per-wave 128x64 output = acc[8][4].
// Slab j read at iter j; staged at iter j-2; gate vmcnt(4).
// LDS swizzle: 16B-chunk ^= (row>>1)&3; source pre-swizzled (dest linear).
// ---------------------------------------------------------------------------
template <int K>
__device__ __forceinline__ void gemm8p_mainloop(
    const u16* __restrict__ A0, const u16* __restrict__ B0,
    u16* lds, f32x4 (&acc)[8][4])
{
  const int tid = threadIdx.x;
  const int w = tid >> 6, l = tid & 63;
  const int wm = w >> 2, wn = w & 3;
  const int fr = l & 15;
  const int laneChunk = ((l >> 4) ^ ((fr >> 1) & 3)) << 3;   // swizzled 16B chunk
  const int laneA = (wm * 128 + fr) * 32 + laneChunk;
  const int laneB = (wn * 64 + fr) * 32 + laneChunk;
  u16* const ldsA = lds;                 // 3 slots x 8192 u16
  u16* const ldsB = lds + 24576;

  const int chunkS = ((tid & 3) ^ ((tid >> 3) & 3)) << 3;    // pre-swizzled src
  const int r0 = tid >> 2;
  const u16* const sA0 = A0 + (size_t)r0 * K + chunkS;
  const u16* const sA1 = A0 + (size_t)(r0 + 128) * K + chunkS;
  const u16* const sB0 = B0 + (size_t)r0 * K + chunkS;
  const u16* const sB1 = B0 + (size_t)(r0 + 128) * K + chunkS;
  const int dOf = w * 512;               // wave-uniform; HW adds lane*16B

#define STAGE_A(j, slot) do {                                                  \
    u16* d_ = ldsA + (slot) * 8192 + dOf;                                      \
    GLL16(sA0 + (j) * 32, d_);                                                 \
    GLL16(sA1 + (j) * 32, d_ + 4096);                                          \
  } while (0)
#define STAGE_B(j, slot) do {                                                  \
    u16* d_ = ldsB + (slot) * 8192 + dOf;                                      \
    GLL16(sB0 + (j) * 32, d_);                                                 \
    GLL16(sB1 + (j) * 32, d_ + 4096);                                          \
  } while (0)

  STAGE_B(0, 0); STAGE_A(0, 0);
  STAGE_B(1, 1); STAGE_A(1, 1);

  constexpr int NS = K / 32;
  int slot = 0;
  for (int j = 0; j < NS; ++j) {
    const int jn = (j + 2 < NS) ? (j + 2) : (NS - 1);   // clamped (dup loads
    int slotn = slot + 2; if (slotn >= 3) slotn -= 3;   //  land in dead slot)

    asm volatile("s_waitcnt vmcnt(4)\n\ts_barrier" ::: "memory");

    const u16* const Ab = ldsA + slot * 8192;
    const u16* const Bb = ldsB + slot * 8192;
    bf16x8 a[4], b[4], a2[4];
#pragma unroll
    for (int i = 0; i < 4; ++i) a[i] = *(const bf16x8*)(Ab + laneA + i * 512);
#pragma unroll
    for (int i = 0; i < 4; ++i) b[i] = *(const bf16x8*)(Bb + laneB + i * 512);
    STAGE_B(jn, slotn);
    __builtin_amdgcn_s_setprio(1);
#pragma unroll
    for (int mi = 0; mi < 4; ++mi)
#pragma unroll
      for (int nj = 0; nj < 4; ++nj)
        acc[mi][nj] = __builtin_amdgcn_mfma_f32_16x16x32_bf16(a[mi], b[nj], acc[mi][nj], 0, 0, 0);
    __builtin_amdgcn_s_setprio(0);

#pragma unroll
    for (int i = 0; i < 4; ++i) a2[i] = *(const bf16x8*)(Ab + laneA + (4 + i) * 512);
    STAGE_A(jn, slotn);
    __builtin_amdgcn_s_setprio(1);
#pragma unroll
    for (int mi = 0; mi < 4; ++mi)
#pragma unroll
      for (int nj = 0; nj < 4; ++nj)
        acc[4 + mi][nj] = __builtin_amdgcn_mfma_f32_16x16x32_bf16(a2[mi], b[nj], acc[4 + mi][nj], 0, 0, 0);
    __builtin_amdgcn_s_setprio(0);
    asm volatile("s_barrier" ::: "memory");

    slot = (slot == 2) ? 0 : slot + 1;
  }
#undef STAGE_A
#undef STAGE_B
}

// ---------------------------------------------------------------------------
// 8-phase 256x128 mainloop (PV): C[256x128] += A[256xK].B[128xK]^T.
// 512 threads = 8 waves (4M x 2N); per-wave 64x64 output = acc[4][4].
// Per slab per wave: A 2 GLL16 + B 1 GLL16 (even); gate vmcnt(3).
// LDS: A 3x16KB + B 3x8KB = 72 KB. Same swizzle as above.
// ---------------------------------------------------------------------------
template <int K>
__device__ __forceinline__ void gemm8p_256x128(
    const u16* __restrict__ A0, const u16* __restrict__ B0,
    u16* lds, f32x4 (&acc)[4][4])
{
  const int tid = threadIdx.x;
  const int w = tid >> 6, l = tid & 63;
  const int wm = w >> 1, wn = w & 1;
  const int fr = l & 15;
  const int laneChunk = ((l >> 4) ^ ((fr >> 1) & 3)) << 3;
  const int laneA = (wm * 64 + fr) * 32 + laneChunk;
  const int laneB = (wn * 64 + fr) * 32 + laneChunk;
  u16* const ldsA = lds;                 // 3 slots x 8192 u16 (16 KB)
  u16* const ldsB = lds + 24576;         // 3 slots x 4096 u16 (8 KB)

  const int chunkS = ((tid & 3) ^ ((tid >> 3) & 3)) << 3;
  const int r0 = tid >> 2;               // 0..127
  const u16* const sA0 = A0 + (size_t)r0 * K + chunkS;
  const u16* const sA1 = A0 + (size_t)(r0 + 128) * K + chunkS;
  const u16* const sB0 = B0 + (size_t)r0 * K + chunkS;
  const int dOf = w * 512;

#define PSTAGE_A(j, slot) do {                                                 \
    u16* d_ = ldsA + (slot) * 8192 + dOf;                                      \
    GLL16(sA0 + (j) * 32, d_);                                                 \
    GLL16(sA1 + (j) * 32, d_ + 4096);                                          \
  } while (0)
#define PSTAGE_B(j, slot) do {                                                 \
    u16* d_ = ldsB + (slot) * 4096 + dOf;                                      \
    GLL16(sB0 + (j) * 32, d_);                                                 \
  } while (0)

  PSTAGE_B(0, 0); PSTAGE_A(0, 0);
  PSTAGE_B(1, 1); PSTAGE_A(1, 1);

  constexpr int NS = K / 32;
  int slot = 0;
  for (int j = 0; j < NS; ++j) {
    const int jn = (j + 2 < NS) ? (j + 2) : (NS - 1);
    int slotn = slot + 2; if (slotn >= 3) slotn -= 3;

    // gate: slab j resident; 3 newer loads (slab j+1) may remain in flight
    asm volatile("s_waitcnt vmcnt(3)\n\ts_barrier" ::: "memory");

    const u16* const Ab = ldsA + slot * 8192;
    const u16* const Bb = ldsB + slot * 4096;
    bf16x8 a[4], b[4];
#pragma unroll
    for (int i = 0; i < 4; ++i) a[i] = *(const bf16x8*)(Ab + laneA + i * 512);
#pragma unroll
    for (int i = 0; i < 4; ++i) b[i] = *(const bf16x8*)(Bb + laneB + i * 512);
    PSTAGE_B(jn, slotn);
    __builtin_amdgcn_s_setprio(1);
#pragma unroll
    for (int mi = 0; mi < 2; ++mi)
#pragma unroll
      for (int nj = 0; nj < 4; ++nj)
        acc[mi][nj] = __builtin_amdgcn_mfma_f32_16x16x32_bf16(a[mi], b[nj], acc[mi][nj], 0, 0, 0);
    __builtin_amdgcn_s_setprio(0);
    PSTAGE_A(jn, slotn);
    __builtin_amdgcn_s_setprio(1);
#pragma unroll
    for (int mi = 2; mi < 4; ++mi)
#pragma unroll
      for (int nj = 0; nj < 4; ++nj)
        acc[mi][nj] = __builtin_amdgcn_mfma_f32_16x16x32_bf16(a[mi], b[nj], acc[mi][nj], 0, 0, 0);
    __builtin_amdgcn_s_setprio(0);
    asm volatile("s_barrier" ::: "memory");

    slot = (slot == 2) ? 0 : slot + 1;
  }
#undef PSTAGE_A
#undef PSTAGE_B
}

// ---------------------------------------------------------------------------
// Kernels
// ---------------------------------------------------------------------------

__global__ void convert_x_kernel(const float* __restrict__ x, u16* __restrict__ xb) {
  int i = blockIdx.x * 256 + threadIdx.x;
  float4 f = ((const float4*)x)[i];
  u16x4 o = { f2bf(f.x), f2bf(f.y), f2bf(f.z), f2bf(f.w) };
  ((u16x4*)xb)[i] = o;
}

__global__ void convw_kernel(const float* __restrict__ W, u16* __restrict__ wT) {
  __shared__ float tile[32][33];
  const int mtx = blockIdx.z;
  const int e0 = blockIdx.x * 32, d0 = blockIdx.y * 32;
  const int tx = threadIdx.x, ty = threadIdx.y;
  const float* Wm = W + (size_t)mtx * 262144;
#pragma unroll
  for (int i = 0; i < 32; i += 8)
    tile[ty + i][tx] = Wm[(size_t)(d0 + ty + i) * 512 + e0 + tx];
  __syncthreads();
  u16* T = wT + (size_t)mtx * 262144;
#pragma unroll
  for (int i = 0; i < 32; i += 8)
    T[(size_t)(e0 + ty + i) * 512 + d0 + tx] = f2bf(tile[tx][ty + i]);
}

// QKV via 8-phase 256^2: xb[16384,512] . wT[1536,512]^T
__global__ __launch_bounds__(512, 2) void gemm_qkv8p_kernel(
    const u16* __restrict__ xb, const u16* __restrict__ wT,
    u16* __restrict__ qb, u16* __restrict__ kb, u16* __restrict__ vt)
{
  __shared__ __align__(16) u16 lds[49152];   // 96 KB
  const int n0 = blockIdx.x * 256, m0 = blockIdx.y * 256;
  f32x4 acc[8][4] = {};
  gemm8p_mainloop<512>(xb + (size_t)m0 * 512, wT + (size_t)n0 * 512, lds, acc);

  const int tid = threadIdx.x, w = tid >> 6, l = tid & 63;
  const int wm = w >> 2, wn = w & 3;
  const int which = n0 >> 9;                  // bx: 0,1->q 2,3->k 4,5->v
  const int rb = m0 + wm * 128 + (l >> 4) * 4;
  const int e0 = (n0 & 511) + wn * 64 + (l & 15);
  if (which < 2) {
    u16* dst = which ? kb : qb;
#pragma unroll
    for (int mi = 0; mi < 8; ++mi)
#pragma unroll
      for (int nj = 0; nj < 4; ++nj) {
        const int row = rb + mi * 16;
        const int col = e0 + nj * 16;
#pragma unroll
        for (int r = 0; r < 4; ++r)
          dst[(size_t)(row + r) * 512 + col] = f2bf(acc[mi][nj][r]);
      }
  } else {
#pragma unroll
    for (int mi = 0; mi < 8; ++mi)
#pragma unroll
      for (int nj = 0; nj < 4; ++nj) {
        const int s = rb + mi * 16;             // global row (b*2048+s)
        const int b = s >> 11, sl = s & 2047;
        const int e = e0 + nj * 16;
        u16x4 pk;
#pragma unroll
        for (int r = 0; r < 4; ++r) pk[r] = f2bf(acc[mi][nj][r]);
        *(u16x4*)(vt + (size_t)b * 1048576 + (size_t)e * 2048 + sl) = pk;
      }
  }
}

// scores via 8-phase 256^2: Q[z].K[z]^T * 0.125 -> bf16
__global__ __launch_bounds__(512, 2) void gemm_scores8p_kernel(
    const u16* __restrict__ qb, const u16* __restrict__ kb, u16* __restrict__ attn)
{
  __shared__ __align__(16) u16 lds[49152];   // 96 KB
  const int z = blockIdx.z;
  const int n0 = blockIdx.x * 256, m0 = blockIdx.y * 256;
  f32x4 acc[8][4] = {};
  gemm8p_mainloop<512>(qb + (size_t)z * 1048576 + (size_t)m0 * 512,
                       kb + (size_t)z * 1048576 + (size_t)n0 * 512, lds, acc);

  const int tid = threadIdx.x, w = tid >> 6, l = tid & 63;
  const int wm = w >> 2, wn = w & 3;
  u16* C = attn + (size_t)z * 4194304;
  const int rb = m0 + wm * 128 + (l >> 4) * 4;
  const int cb = n0 + wn * 64 + (l & 15);
#pragma unroll
  for (int mi = 0; mi < 8; ++mi)
#pragma unroll
    for (int nj = 0; nj < 4; ++nj) {
      const int row = rb + mi * 16;
      const int col = cb + nj * 16;
#pragma unroll
      for (int r = 0; r < 4; ++r)
        C[(size_t)(row + r) * 2048 + col] = f2bf(acc[mi][nj][r] * 0.125f);
    }
}

// row softmax in place, bf16 storage, fp32 math. one block per row of 2048.
__global__ __launch_bounds__(256) void softmax_kernel(u16* __restrict__ attn) {
  __shared__ float redm[4], reds[4];
  const size_t row = blockIdx.x;
  u16* p = attn + row * 2048;
  const int t = threadIdx.x, w = t >> 6, l = t & 63;

  uint4 u = ((const uint4*)p)[t];
  u16* us = (u16*)&u;
  float v[8];
#pragma unroll
  for (int i = 0; i < 8; ++i) v[i] = bf2f(us[i]);

  float m = v[0];
#pragma unroll
  for (int i = 1; i < 8; ++i) m = fmaxf(m, v[i]);
  for (int off = 32; off >= 1; off >>= 1) m = fmaxf(m, __shfl_xor(m, off));
  if (l == 0) redm[w] = m;
  __syncthreads();
  m = fmaxf(fmaxf(redm[0], redm[1]), fmaxf(redm[2], redm[3]));

  float e[8], s = 0.f;
#pragma unroll
  for (int i = 0; i < 8; ++i) { e[i] = __expf(v[i] - m); s += e[i]; }
  for (int off = 32; off >= 1; off >>= 1) s += __shfl_xor(s, off);
  if (l == 0) reds[w] = s;
  __syncthreads();
  s = reds[0] + reds[1] + reds[2] + reds[3];
  const float inv = 1.f / s;

#pragma unroll
  for (int i = 0; i < 8; ++i) us[i] = f2bf(e[i] * inv);
  ((uint4*)p)[t] = u;
}

// out[z] = P[z][2048,2048] . V[z] (V transposed: vt[z][512][2048]) -> f32
// 8-phase 256x128 tiles; block swizzle: id&7 -> z (XCD-resident vt_z + P reuse)
__global__ __launch_bounds__(512, 2) void gemm_pv8p_kernel(
    const u16* __restrict__ attn, const u16* __restrict__ vt, float* __restrict__ out)
{
  __shared__ __align__(16) u16 lds[36864];   // 72 KB
  const int id = blockIdx.x;                 // 256 blocks
  const int z = id & 7;                      // id%8 = XCD (T1): one z per XCD
  const int j = id >> 3;                     // 0..31
  const int n0 = (j & 3) * 128;              // 4 n-tiles
  const int m0 = (j >> 2) * 256;             // 8 m-tiles
  f32x4 acc[4][4] = {};
  gemm8p_256x128<2048>(attn + (size_t)z * 4194304 + (size_t)m0 * 2048,
                       vt + (size_t)z * 1048576 + (size_t)n0 * 2048, lds, acc);

  const int tid = threadIdx.x, w = tid >> 6, l = tid & 63;
  const int wm = w >> 1, wn = w & 1;
  float* C = out + (size_t)z * 1048576;
  const int rb = m0 + wm * 64 + (l >> 4) * 4;
  const int cb = n0 + wn * 64 + (l & 15);
#pragma unroll
  for (int mi = 0; mi < 4; ++mi)
#pragma unroll
    for (int nj = 0; nj < 4; ++nj) {
      const int row = rb + mi * 16;
      const int col = cb + nj * 16;
#pragma unroll
      for (int r = 0; r < 4; ++r)
        C[(size_t)(row + r) * 512 + col] = acc[mi][nj][r];
    }
}

// ---------------------------------------------------------------------------
extern "C" void kernel_launch(void* const* d_in, const int* in_sizes, int n_in,
                              void* d_out, int out_size, void* d_ws, size_t ws_size,
                              hipStream_t stream) {
  const float* x = (const float*)d_in[0];   // [8,2048,512]
  const float* W = (const float*)d_in[1];   // [3,512,512]
  float* out = (float*)d_out;               // [8,2048,512]

  if (ws_size < 117440512) return;          // 112 MiB needed
  u16* wsu  = (u16*)d_ws;
  u16* qb   = wsu;
  u16* kb   = qb + 8388608;
  u16* vt   = kb + 8388608;
  u16* attn = vt + 8388608;
  u16* xb   = attn;                         // alias: dead before scores written
  u16* wT   = attn + 8388608;               // alias: dead before scores written

  convert_x_kernel<<<8192, 256, 0, stream>>>(x, xb);
  convw_kernel<<<dim3(16, 16, 3), dim3(32, 8), 0, stream>>>(W, wT);
  gemm_qkv8p_kernel<<<dim3(6, 64), 512, 0, stream>>>(xb, wT, qb, kb, vt);
  gemm_scores8p_kernel<<<dim3(8, 8, 8), 512, 0, stream>>>(qb, kb, attn);
  softmax_kernel<<<16384, 256, 0, stream>>>(attn);
  gemm_pv8p_kernel<<<256, 512, 0, stream>>>(attn, vt, out);
}

// Round 6
// 146.436 us; speedup vs baseline: 1.3268x; 1.0655x over previous
//
#include <hip/hip_runtime.h>

// SelfAttention: x[8,2048,512] f32, W[3,512,512] f32 -> out[8,2048,512] f32
// scale = 1/sqrt(64) = 0.125
//
// R6: all three GEMMs now use the validated 8-phase 256x128 mainloop
// (R5's PV structure: 72KB LDS -> 2 blocks/CU, counted vmcnt(3) gate,
// XOR-swizzled LDS, setprio). scores: z-per-XCD swizzle (Q+K 4MB L2-res).
// qkv: batch-per-XCD swizzle (x panel 2MB + wT 1.5MB L2-res).
// R5 lesson: 256^2 tile (96KB LDS, 1 blk/CU) was latency-starved at K=512
// (MfmaUtil 27.7%); 256x128 at 2 blk/CU is the proven shape (PV ~900 TF).

typedef unsigned short u16;
typedef unsigned int u32;

using bf16x8 = __attribute__((ext_vector_type(8))) short;   // 8 bf16 (4 VGPRs)
using f32x4  = __attribute__((ext_vector_type(4))) float;
using u16x4  = __attribute__((ext_vector_type(4))) u16;

__device__ __forceinline__ u16 f2bf(float f) {
  u32 u = __float_as_uint(f);
  u32 r = (u + 0x7FFFu + ((u >> 16) & 1u)) >> 16;   // RNE
  return (u16)r;
}
__device__ __forceinline__ float bf2f(u16 h) {
  return __uint_as_float(((u32)h) << 16);
}

#define GLL16(src, dst)                                                        \
  __builtin_amdgcn_global_load_lds(                                            \
      (const __attribute__((address_space(1))) void*)(src),                    \
      (__attribute__((address_space(3))) void*)(dst), 16, 0, 0)

// ---------------------------------------------------------------------------
// 8-phase 256x128 mainloop: C[256x128] += A[256xK].B[128xK]^T, row-major.
// 512 threads = 8 waves (4M x 2N); per-wave 64x64 output = acc[4][4].
// K-slab [32] staged 2 ahead into 3 slots; per slab per wave: A 2 GLL16 +
// B 1 GLL16; gate s_waitcnt vmcnt(3) (slab j resident, j+1 in flight).
// LDS: A 3x16KB + B 3x8KB = 72 KB -> 2 blocks/CU.
// Swizzle: 16B-chunk ^= (row>>1)&3 on read; source pre-swizzled (dest linear).
// ---------------------------------------------------------------------------
template <int K>
__device__ __forceinline__ void gemm8p_256x128(
    const u16* __restrict__ A0, const u16* __restrict__ B0,
    u16* lds, f32x4 (&acc)[4][4])
{
  const int tid = threadIdx.x;
  const int w = tid >> 6, l = tid & 63;
  const int wm = w >> 1, wn = w & 1;
  const int fr = l & 15;
  const int laneChunk = ((l >> 4) ^ ((fr >> 1) & 3)) << 3;
  const int laneA = (wm * 64 + fr) * 32 + laneChunk;
  const int laneB = (wn * 64 + fr) * 32 + laneChunk;
  u16* const ldsA = lds;                 // 3 slots x 8192 u16 (16 KB)
  u16* const ldsB = lds + 24576;         // 3 slots x 4096 u16 (8 KB)

  const int chunkS = ((tid & 3) ^ ((tid >> 3) & 3)) << 3;
  const int r0 = tid >> 2;               // 0..127
  const u16* const sA0 = A0 + (size_t)r0 * K + chunkS;
  const u16* const sA1 = A0 + (size_t)(r0 + 128) * K + chunkS;
  const u16* const sB0 = B0 + (size_t)r0 * K + chunkS;
  const int dOf = w * 512;

#define PSTAGE_A(j, slot) do {                                                 \
    u16* d_ = ldsA + (slot) * 8192 + dOf;                                      \
    GLL16(sA0 + (j) * 32, d_);                                                 \
    GLL16(sA1 + (j) * 32, d_ + 4096);                                          \
  } while (0)
#define PSTAGE_B(j, slot) do {                                                 \
    u16* d_ = ldsB + (slot) * 4096 + dOf;                                      \
    GLL16(sB0 + (j) * 32, d_);                                                 \
  } while (0)

  PSTAGE_B(0, 0); PSTAGE_A(0, 0);
  PSTAGE_B(1, 1); PSTAGE_A(1, 1);

  constexpr int NS = K / 32;
  int slot = 0;
  for (int j = 0; j < NS; ++j) {
    const int jn = (j + 2 < NS) ? (j + 2) : (NS - 1);   // clamped (dups land
    int slotn = slot + 2; if (slotn >= 3) slotn -= 3;   //  in dead slot)

    // gate: slab j resident; 3 newer loads (slab j+1) may remain in flight
    asm volatile("s_waitcnt vmcnt(3)\n\ts_barrier" ::: "memory");

    const u16* const Ab = ldsA + slot * 8192;
    const u16* const Bb = ldsB + slot * 4096;
    bf16x8 a[4], b[4];
#pragma unroll
    for (int i = 0; i < 4; ++i) a[i] = *(const bf16x8*)(Ab + laneA + i * 512);
#pragma unroll
    for (int i = 0; i < 4; ++i) b[i] = *(const bf16x8*)(Bb + laneB + i * 512);
    PSTAGE_B(jn, slotn);
    __builtin_amdgcn_s_setprio(1);
#pragma unroll
    for (int mi = 0; mi < 2; ++mi)
#pragma unroll
      for (int nj = 0; nj < 4; ++nj)
        acc[mi][nj] = __builtin_amdgcn_mfma_f32_16x16x32_bf16(a[mi], b[nj], acc[mi][nj], 0, 0, 0);
    __builtin_amdgcn_s_setprio(0);
    PSTAGE_A(jn, slotn);
    __builtin_amdgcn_s_setprio(1);
#pragma unroll
    for (int mi = 2; mi < 4; ++mi)
#pragma unroll
      for (int nj = 0; nj < 4; ++nj)
        acc[mi][nj] = __builtin_amdgcn_mfma_f32_16x16x32_bf16(a[mi], b[nj], acc[mi][nj], 0, 0, 0);
    __builtin_amdgcn_s_setprio(0);
    asm volatile("s_barrier" ::: "memory");

    slot = (slot == 2) ? 0 : slot + 1;
  }
#undef PSTAGE_A
#undef PSTAGE_B
}

// ---------------------------------------------------------------------------
// Kernels
// ---------------------------------------------------------------------------

__global__ void convert_x_kernel(const float* __restrict__ x, u16* __restrict__ xb) {
  int i = blockIdx.x * 256 + threadIdx.x;
  float4 f = ((const float4*)x)[i];
  u16x4 o = { f2bf(f.x), f2bf(f.y), f2bf(f.z), f2bf(f.w) };
  ((u16x4*)xb)[i] = o;
}

__global__ void convw_kernel(const float* __restrict__ W, u16* __restrict__ wT) {
  __shared__ float tile[32][33];
  const int mtx = blockIdx.z;
  const int e0 = blockIdx.x * 32, d0 = blockIdx.y * 32;
  const int tx = threadIdx.x, ty = threadIdx.y;
  const float* Wm = W + (size_t)mtx * 262144;
#pragma unroll
  for (int i = 0; i < 32; i += 8)
    tile[ty + i][tx] = Wm[(size_t)(d0 + ty + i) * 512 + e0 + tx];
  __syncthreads();
  u16* T = wT + (size_t)mtx * 262144;
#pragma unroll
  for (int i = 0; i < 32; i += 8)
    T[(size_t)(e0 + ty + i) * 512 + d0 + tx] = f2bf(tile[tx][ty + i]);
}

// QKV: xb[16384,512] . wT[1536,512]^T via 256x128 tiles.
// Swizzle: xcd = id&7 owns batch xcd (m-rows xcd*2048..+2048): x 2MB + wT
// 1.5MB L2-resident. 768 blocks, 2/CU.
__global__ __launch_bounds__(512, 4) void gemm_qkv128_kernel(
    const u16* __restrict__ xb, const u16* __restrict__ wT,
    u16* __restrict__ qb, u16* __restrict__ kb, u16* __restrict__ vt)
{
  __shared__ __align__(16) u16 lds[36864];   // 72 KB
  const int id = blockIdx.x;                 // 768 blocks
  const int xcd = id & 7, t = id >> 3;       // t: 0..95
  const int n0 = (t % 12) * 128;
  const int m0 = (xcd * 8 + t / 12) * 256;
  f32x4 acc[4][4] = {};
  gemm8p_256x128<512>(xb + (size_t)m0 * 512, wT + (size_t)n0 * 512, lds, acc);

  const int tid = threadIdx.x, w = tid >> 6, l = tid & 63;
  const int wm = w >> 1, wn = w & 1;
  const int which = n0 >> 9;                 // 0=q 1=k 2=v
  const int eb = (n0 & 511) + wn * 64 + (l & 15);
  const int rb = m0 + wm * 64 + (l >> 4) * 4;
  if (which < 2) {
    u16* dst = which ? kb : qb;
#pragma unroll
    for (int mi = 0; mi < 4; ++mi)
#pragma unroll
      for (int nj = 0; nj < 4; ++nj) {
        const int row = rb + mi * 16;
        const int col = eb + nj * 16;
#pragma unroll
        for (int r = 0; r < 4; ++r)
          dst[(size_t)(row + r) * 512 + col] = f2bf(acc[mi][nj][r]);
      }
  } else {
#pragma unroll
    for (int mi = 0; mi < 4; ++mi)
#pragma unroll
      for (int nj = 0; nj < 4; ++nj) {
        const int s = rb + mi * 16;            // global row (b*2048+s)
        const int b = s >> 11, sl = s & 2047;
        const int e = eb + nj * 16;
        u16x4 pk;
#pragma unroll
        for (int r = 0; r < 4; ++r) pk[r] = f2bf(acc[mi][nj][r]);
        *(u16x4*)(vt + (size_t)b * 1048576 + (size_t)e * 2048 + sl) = pk;
      }
  }
}

// scores[z] = Q[z].K[z]^T * 0.125 -> bf16, 256x128 tiles.
// Swizzle: z = id&7 -> each XCD keeps its batch's Q+K (4MB) L2-resident.
__global__ __launch_bounds__(512, 4) void gemm_scores128_kernel(
    const u16* __restrict__ qb, const u16* __restrict__ kb, u16* __restrict__ attn)
{
  __shared__ __align__(16) u16 lds[36864];   // 72 KB
  const int id = blockIdx.x;                 // 1024 blocks
  const int z = id & 7, t = id >> 3;         // t: 0..127
  const int n0 = (t & 15) * 128;
  const int m0 = (t >> 4) * 256;
  f32x4 acc[4][4] = {};
  gemm8p_256x128<512>(qb + (size_t)z * 1048576 + (size_t)m0 * 512,
                      kb + (size_t)z * 1048576 + (size_t)n0 * 512, lds, acc);

  const int tid = threadIdx.x, w = tid >> 6, l = tid & 63;
  const int wm = w >> 1, wn = w & 1;
  u16* C = attn + (size_t)z * 4194304;
  const int rb = m0 + wm * 64 + (l >> 4) * 4;
  const int cb = n0 + wn * 64 + (l & 15);
#pragma unroll
  for (int mi = 0; mi < 4; ++mi)
#pragma unroll
    for (int nj = 0; nj < 4; ++nj) {
      const int row = rb + mi * 16;
      const int col = cb + nj * 16;
#pragma unroll
      for (int r = 0; r < 4; ++r)
        C[(size_t)(row + r) * 2048 + col] = f2bf(acc[mi][nj][r] * 0.125f);
    }
}

// row softmax in place, bf16 storage, fp32 math. one block per row of 2048.
__global__ __launch_bounds__(256) void softmax_kernel(u16* __restrict__ attn) {
  __shared__ float redm[4], reds[4];
  const size_t row = blockIdx.x;
  u16* p = attn + row * 2048;
  const int t = threadIdx.x, w = t >> 6, l = t & 63;

  uint4 u = ((const uint4*)p)[t];
  u16* us = (u16*)&u;
  float v[8];
#pragma unroll
  for (int i = 0; i < 8; ++i) v[i] = bf2f(us[i]);

  float m = v[0];
#pragma unroll
  for (int i = 1; i < 8; ++i) m = fmaxf(m, v[i]);
  for (int off = 32; off >= 1; off >>= 1) m = fmaxf(m, __shfl_xor(m, off));
  if (l == 0) redm[w] = m;
  __syncthreads();
  m = fmaxf(fmaxf(redm[0], redm[1]), fmaxf(redm[2], redm[3]));

  float e[8], s = 0.f;
#pragma unroll
  for (int i = 0; i < 8; ++i) { e[i] = __expf(v[i] - m); s += e[i]; }
  for (int off = 32; off >= 1; off >>= 1) s += __shfl_xor(s, off);
  if (l == 0) reds[w] = s;
  __syncthreads();
  s = reds[0] + reds[1] + reds[2] + reds[3];
  const float inv = 1.f / s;

#pragma unroll
  for (int i = 0; i < 8; ++i) us[i] = f2bf(e[i] * inv);
  ((uint4*)p)[t] = u;
}

// out[z] = P[z][2048,2048] . V[z] (V transposed: vt[z][512][2048]) -> f32
// 8-phase 256x128 tiles; block swizzle: id&7 -> z (XCD-resident vt_z + P reuse)
__global__ __launch_bounds__(512, 2) void gemm_pv8p_kernel(
    const u16* __restrict__ attn, const u16* __restrict__ vt, float* __restrict__ out)
{
  __shared__ __align__(16) u16 lds[36864];   // 72 KB
  const int id = blockIdx.x;                 // 256 blocks
  const int z = id & 7;                      // id%8 = XCD (T1): one z per XCD
  const int j = id >> 3;                     // 0..31
  const int n0 = (j & 3) * 128;              // 4 n-tiles
  const int m0 = (j >> 2) * 256;             // 8 m-tiles
  f32x4 acc[4][4] = {};
  gemm8p_256x128<2048>(attn + (size_t)z * 4194304 + (size_t)m0 * 2048,
                       vt + (size_t)z * 1048576 + (size_t)n0 * 2048, lds, acc);

  const int tid = threadIdx.x, w = tid >> 6, l = tid & 63;
  const int wm = w >> 1, wn = w & 1;
  float* C = out + (size_t)z * 1048576;
  const int rb = m0 + wm * 64 + (l >> 4) * 4;
  const int cb = n0 + wn * 64 + (l & 15);
#pragma unroll
  for (int mi = 0; mi < 4; ++mi)
#pragma unroll
    for (int nj = 0; nj < 4; ++nj) {
      const int row = rb + mi * 16;
      const int col = cb + nj * 16;
#pragma unroll
      for (int r = 0; r < 4; ++r)
        C[(size_t)(row + r) * 512 + col] = acc[mi][nj][r];
    }
}

// ---------------------------------------------------------------------------
extern "C" void kernel_launch(void* const* d_in, const int* in_sizes, int n_in,
                              void* d_out, int out_size, void* d_ws, size_t ws_size,
                              hipStream_t stream) {
  const float* x = (const float*)d_in[0];   // [8,2048,512]
  const float* W = (const float*)d_in[1];   // [3,512,512]
  float* out = (float*)d_out;               // [8,2048,512]

  if (ws_size < 117440512) return;          // 112 MiB needed
  u16* wsu  = (u16*)d_ws;
  u16* qb   = wsu;
  u16* kb   = qb + 8388608;
  u16* vt   = kb + 8388608;
  u16* attn = vt + 8388608;
  u16* xb   = attn;                         // alias: dead before scores written
  u16* wT   = attn + 8388608;               // alias: dead before scores written

  convert_x_kernel<<<8192, 256, 0, stream>>>(x, xb);
  convw_kernel<<<dim3(16, 16, 3), dim3(32, 8), 0, stream>>>(W, wT);
  gemm_qkv128_kernel<<<768, 512, 0, stream>>>(xb, wT, qb, kb, vt);
  gemm_scores128_kernel<<<1024, 512, 0, stream>>>(qb, kb, attn);
  softmax_kernel<<<16384, 256, 0, stream>>>(attn);
  gemm_pv8p_kernel<<<256, 512, 0, stream>>>(attn, vt, out);
}